// Round 1
// baseline (137.565 us; speedup 1.0000x reference)
//
#include <hip/hip_runtime.h>
#include <float.h>

// Problem constants from the reference
#define ROW 1000
#define CHUNKS_L 500      // float4 chunks of logits per user (2 elements each)
#define CHUNKS_D 250      // int4 chunks of dup per user (4 elements each)
#define TOP_K 10
#define NUM_EVAL_NEG 999
#define USERS_PER_BLOCK 4

// NOTE: __builtin_nontemporal_load was tried (R4, prev session) and FAILED the
// harness's post-timing re-validation (stale reads vs input-restore). Plain loads.
typedef float vfloat4 __attribute__((ext_vector_type(4)));
typedef int   vint4   __attribute__((ext_vector_type(4)));

// One wave (64 lanes) per user; 4 users per 256-thread block.
//
// count = #{j : masked[j] > masked[0]}  (stable argsort tie-break favors idx 0)
// Factorized:  count = sum_j gt[j] - sum_j gt[j]*d[j],   gt[j] = (l[j] > x0)
// The first term needs only logits; gt-bits are captured in wave-uniform
// __ballot masks (SGPRs), so BOTH passes use fully-contiguous 1KB wave loads
// (vs the previous stride-32B logit loads that doubled L1 line-transactions).
__global__ __launch_bounds__(256) void metric_kernel(
    const float* __restrict__ logits,   // (N*ROW, 1, 2) flat
    const int*   __restrict__ dup,      // (N*ROW, 1, 1) flat
    float* __restrict__ out,            // [in_top_k(N) | ndcg(N) | weights(N)]
    int num_users)
{
    const int tid  = threadIdx.x;
    const int lane = tid & 63;
    const int user = blockIdx.x * USERS_PER_BLOCK + (tid >> 6);
    if (user >= num_users) return;   // wave-uniform (all lanes same user)

    const float BIG_NEG = -FLT_MAX;  // jnp.finfo(float32).min
    const long long base = (long long)user * ROW;

    // masked value of element 0 (one cache-served load per wave)
    const int   d0 = dup[base];
    const float l0 = logits[2 * base + 1];
    const float x0 = d0 ? BIG_NEG : l0;

    // base*8 and base*4 bytes are 16-aligned (8000 % 16 == 0, 4000 % 16 == 0)
    const vfloat4* lg4 = reinterpret_cast<const vfloat4*>(logits + 2 * base);
    const vint4*   dp4 = reinterpret_cast<const vint4*>(dup + base);

    // ---- pass 1: logits, contiguous float4 chunks; gt-bits -> ballots ----
    // chunk c holds elements 2c (at .y) and 2c+1 (at .w)
    unsigned long long be[8], bo[8];   // wave-uniform -> SGPR pairs
    #pragma unroll
    for (int k = 0; k < 8; ++k) {
        const int c  = 64 * k + lane;
        const int cc = (c < CHUNKS_L) ? c : (CHUNKS_L - 1);  // branchless tail clamp
        const vfloat4 a = lg4[cc];
        const bool valid = (c < CHUNKS_L);
        be[k] = __ballot(valid && (a.y > x0));   // even elements  2c
        bo[k] = __ballot(valid && (a.w > x0));   // odd  elements  2c+1
    }

    int cnt1 = 0;   // sum_j gt[j]  (wave-uniform scalar math)
    #pragma unroll
    for (int k = 0; k < 8; ++k)
        cnt1 += __popcll(be[k]) + __popcll(bo[k]);

    // ---- pass 2: dup, contiguous int4 chunks; cross term + dup sum ----
    // chunk g holds elements 4g..4g+3; their gt-bits live at
    //   word k = 2m + (lane>>5), bits i=(2*lane)&63 (even) / i (odd) and i+1
    int cross = 0, dsum = 0;
    const int  i  = (2 * lane) & 63;
    const bool hi = (lane & 32) != 0;
    #pragma unroll
    for (int m = 0; m < 4; ++m) {
        const int g  = 64 * m + lane;
        const int gc = (g < CHUNKS_D) ? g : (CHUNKS_D - 1);  // branchless tail clamp
        const vint4 d = dp4[gc];
        const int v = (g < CHUNKS_D) ? 1 : 0;   // zero out clamped duplicate lanes
        const unsigned long long we = hi ? be[2*m + 1] : be[2*m];
        const unsigned long long wo = hi ? bo[2*m + 1] : bo[2*m];
        const unsigned re = (unsigned)(we >> i);
        const unsigned ro = (unsigned)(wo >> i);
        cross += v * ((d.x & re & 1) + (d.y & ro & 1)
                    + ((d.z & (re >> 1)) & 1) + ((d.w & (ro >> 1)) & 1));
        dsum  += v * (d.x + d.y + d.z + d.w);
    }

    // wave-64 butterfly reduce (no LDS, no syncthreads)
    #pragma unroll
    for (int off = 32; off > 0; off >>= 1) {
        cross += __shfl_down(cross, off, 64);
        dsum  += __shfl_down(dsum, off, 64);
    }

    if (lane == 0) {
        const float pos  = (float)(cnt1 - cross);
        const float itk  = (pos < (float)TOP_K) ? 1.0f : 0.0f;
        const float ndcg = (itk != 0.0f) ? (0.69314718055994530942f / logf(pos + 2.0f)) : 0.0f;
        const float w    = (dsum != NUM_EVAL_NEG) ? 1.0f : 0.0f;
        out[user]                 = itk;
        out[num_users + user]     = ndcg;
        out[2 * num_users + user] = w;
    }
}

extern "C" void kernel_launch(void* const* d_in, const int* in_sizes, int n_in,
                              void* d_out, int out_size, void* d_ws, size_t ws_size,
                              hipStream_t stream) {
    const float* logits = (const float*)d_in[0];  // (N*ROW, 1, 2) fp32
    const int*   dup    = (const int*)d_in[1];    // (N*ROW, 1, 1) int32
    float* out = (float*)d_out;                   // 3*N floats

    const int num_users = in_sizes[0] / (2 * ROW);
    const int grid = (num_users + USERS_PER_BLOCK - 1) / USERS_PER_BLOCK;

    metric_kernel<<<grid, 256, 0, stream>>>(logits, dup, out, num_users);
}

// Round 2
// 110.019 us; speedup vs baseline: 1.2504x; 1.2504x over previous
//
#include <hip/hip_runtime.h>
#include <float.h>

// Problem constants from the reference
#define ROW 1000
#define CHUNKS_L 500      // float4 chunks of logits per user (2 elements each)
#define CHUNKS_D 250      // int4 chunks of dup per user (4 elements each)
#define TOP_K 10
#define NUM_EVAL_NEG 999
#define USERS_PER_BLOCK 4

// NOTE: __builtin_nontemporal_load was tried (prev session) and FAILED the
// harness's post-timing re-validation (stale reads vs input-restore). Plain loads.
//
// R1 post-mortem: persistent be[8]/bo[8] u64 arrays were demoted to LDS+scratch
// (LDS_Block_Size=16384, WRITE_SIZE=33MB of spill, VGPR=32) -> 49us latency-bound.
// R2: no persistent ballot state, all 12 loads issued up-front (12-deep MLP),
// ballot+popcount instead of shfl (zero DS ops), launch_bounds allows 128 VGPR.
typedef float vfloat4 __attribute__((ext_vector_type(4)));
typedef int   vint4   __attribute__((ext_vector_type(4)));

// One wave (64 lanes) per user; 4 users per 256-thread block.
// count = #{j : masked[j] > masked[0]} = sum_j (dup[j]==0 && l[j] > x0)
// Logit gt-bits are captured in wave-uniform ballot masks and consumed
// immediately per 256-element group; cnt/dsum accumulate as wave-uniform
// popcounts of ballots (no shuffle reduction, no LDS anywhere).
__global__ __launch_bounds__(256, 4) void metric_kernel(
    const float* __restrict__ logits,   // (N*ROW, 1, 2) flat
    const int*   __restrict__ dup,      // (N*ROW, 1, 1) flat
    float* __restrict__ out,            // [in_top_k(N) | ndcg(N) | weights(N)]
    int num_users)
{
    const int tid  = threadIdx.x;
    const int lane = tid & 63;
    const int user = blockIdx.x * USERS_PER_BLOCK + (tid >> 6);
    if (user >= num_users) return;   // wave-uniform (all lanes same user)

    const long long base = (long long)user * ROW;
    // base*8 and base*4 bytes are 16-aligned (8000 % 16 == 0, 4000 % 16 == 0)
    const vfloat4* lg4 = reinterpret_cast<const vfloat4*>(logits + 2 * base);
    const vint4*   dp4 = reinterpret_cast<const vint4*>(dup + base);

    // ---- issue ALL 12 contiguous 1KB wave-loads up front (12-deep MLP) ----
    // chunk c of lg4 holds elements 2c (.y) and 2c+1 (.w); chunk g of dp4
    // holds dup of elements 4g..4g+3. Tail lanes clamp (re-read last chunk)
    // and are predicated out of the ballots below.
    vfloat4 A[8];   // fully static indexing -> registers
    #pragma unroll
    for (int k = 0; k < 8; ++k) {
        const int c = 64 * k + lane;                     // only k=7 partial
        A[k] = lg4[(c < CHUNKS_L) ? c : (CHUNKS_L - 1)];
    }
    vint4 D[4];
    #pragma unroll
    for (int m = 0; m < 4; ++m) {
        const int g = 64 * m + lane;                     // only m=3 partial
        D[m] = dp4[(g < CHUNKS_D) ? g : (CHUNKS_D - 1)];
    }

    // masked pivot x0 from already-loaded data (no extra serial loads)
    const int   d0 = __builtin_amdgcn_readfirstlane(D[0].x);
    const float l0 = __uint_as_float(
        __builtin_amdgcn_readfirstlane(__float_as_uint(A[0].y)));
    const float x0 = d0 ? -FLT_MAX : l0;   // jnp.finfo(float32).min

    const bool hi = (lane & 32) != 0;
    const int  i  = (2 * lane) & 63;

    int cnt = 0, dsum = 0;   // wave-uniform via ballot+popcount
    #pragma unroll
    for (int m = 0; m < 4; ++m) {
        // group m = elements [256m, 256m+256):
        //   A[2m]   bit l <-> elem 256m + 2l       (beL/boL)
        //   A[2m+1] bit l <-> elem 256m + 128 + 2l (beH/boH)
        //   D[m] lane g=64m+lane <-> elems 4g..4g+3
        const vfloat4 a = A[2 * m];
        const vfloat4 b = A[2 * m + 1];
        const vint4   d = D[m];
        const bool vB = (128 * m + 64 + lane) < CHUNKS_L;   // only m=3 partial
        const unsigned long long beL = __ballot(a.y > x0);
        const unsigned long long boL = __ballot(a.w > x0);
        const unsigned long long beH = __ballot(vB && (b.y > x0));
        const unsigned long long boH = __ballot(vB && (b.w > x0));
        // gt-bits of my 4 dup elements: word (hi ? H : L), bits i and i+1
        const unsigned long long we = hi ? beH : beL;
        const unsigned long long wo = hi ? boH : boL;
        const unsigned re = (unsigned)(we >> i);
        const unsigned ro = (unsigned)(wo >> i);
        const bool vD = (64 * m + lane) < CHUNKS_D;         // only m=3 partial
        cnt  += __popcll(__ballot(vD && (d.x == 0) && (re & 1)));
        cnt  += __popcll(__ballot(vD && (d.y == 0) && (ro & 1)));
        cnt  += __popcll(__ballot(vD && (d.z == 0) && ((re >> 1) & 1)));
        cnt  += __popcll(__ballot(vD && (d.w == 0) && ((ro >> 1) & 1)));
        dsum += __popcll(__ballot(vD && (d.x != 0)));
        dsum += __popcll(__ballot(vD && (d.y != 0)));
        dsum += __popcll(__ballot(vD && (d.z != 0)));
        dsum += __popcll(__ballot(vD && (d.w != 0)));
    }

    if (lane == 0) {
        const float pos  = (float)cnt;
        const float itk  = (pos < (float)TOP_K) ? 1.0f : 0.0f;
        const float ndcg = (itk != 0.0f)
            ? (0.69314718055994530942f / logf(pos + 2.0f)) : 0.0f;
        const float w    = (dsum != NUM_EVAL_NEG) ? 1.0f : 0.0f;
        out[user]                 = itk;
        out[num_users + user]     = ndcg;
        out[2 * num_users + user] = w;
    }
}

extern "C" void kernel_launch(void* const* d_in, const int* in_sizes, int n_in,
                              void* d_out, int out_size, void* d_ws, size_t ws_size,
                              hipStream_t stream) {
    const float* logits = (const float*)d_in[0];  // (N*ROW, 1, 2) fp32
    const int*   dup    = (const int*)d_in[1];    // (N*ROW, 1, 1) int32
    float* out = (float*)d_out;                   // 3*N floats

    const int num_users = in_sizes[0] / (2 * ROW);
    const int grid = (num_users + USERS_PER_BLOCK - 1) / USERS_PER_BLOCK;

    metric_kernel<<<grid, 256, 0, stream>>>(logits, dup, out, num_users);
}

// Round 3
// 109.982 us; speedup vs baseline: 1.2508x; 1.0003x over previous
//
#include <hip/hip_runtime.h>
#include <float.h>

// Problem constants from the reference
#define ROW 1000
#define CHUNKS_L 500      // float4 chunks of logits per user (2 elements each)
#define CHUNKS_D 250      // int4 chunks of dup per user (4 elements each)
#define TOP_K 10
#define NUM_EVAL_NEG 999
#define USERS_PER_BLOCK 4

// NOTE: __builtin_nontemporal_load was tried (prev session) and FAILED the
// harness's post-timing re-validation (stale reads vs input-restore). Plain loads.
//
// R1: persistent u64 ballot arrays -> LDS+scratch demotion (33MB spill) -> 49us.
// R2: ballot+popcount, 12 loads up-front, no LDS -> kernel ~21.6us (inferred via
//     R1 calibration: end-to-end 137.6 @ 49.2us kernel -> harness-fixed ~88.4us).
// R3: grid is exactly 8 blocks/CU; single-round residency needs <=64 VGPR/wave.
//     1-deep pipeline (issue group m+1, consume group m; peak 2 groups = 40 VGPR
//     payload) + __launch_bounds__(256,8) to pin 64 VGPR -> 32 waves/CU.
typedef float vfloat4 __attribute__((ext_vector_type(4)));
typedef int   vint4   __attribute__((ext_vector_type(4)));

// One wave (64 lanes) per user; 4 users per 256-thread block.
// count = #{j : masked[j] > masked[0]} = sum_j (dup[j]==0 && l[j] > x0)
// Group m = elements [256m, 256m+256):
//   aL = lg4[128m+lane]  -> elems 256m+2*lane   (.y) / +1 (.w)
//   aH = lg4[128m+64+l]  -> elems 256m+128+2l   (.y) / +1 (.w)
//   dv = dp4[64m+lane]   -> dup of elems 256m+4*lane .. +3
// gt-bit of even elem 256m+4*lane lives at bit (2*lane)&63 of (lane<32 ? beL : beH).
__global__ __launch_bounds__(256, 8) void metric_kernel(
    const float* __restrict__ logits,   // (N*ROW, 1, 2) flat
    const int*   __restrict__ dup,      // (N*ROW, 1, 1) flat
    float* __restrict__ out,            // [in_top_k(N) | ndcg(N) | weights(N)]
    int num_users)
{
    const int tid  = threadIdx.x;
    const int lane = tid & 63;
    const int user = blockIdx.x * USERS_PER_BLOCK + (tid >> 6);
    if (user >= num_users) return;   // wave-uniform (all lanes same user)

    const long long base = (long long)user * ROW;
    // base*8 and base*4 bytes are 16-aligned (8000 % 16 == 0, 4000 % 16 == 0)
    const vfloat4* lg4 = reinterpret_cast<const vfloat4*>(logits + 2 * base);
    const vint4*   dp4 = reinterpret_cast<const vint4*>(dup + base);

    // ---- prologue: groups 0 and 1 in flight (6 loads, 40 VGPR payload) ----
    vfloat4 aL0 = lg4[lane];
    vfloat4 aH0 = lg4[64 + lane];
    vint4   dv0 = dp4[lane];
    vfloat4 aL1 = lg4[128 + lane];
    vfloat4 aH1 = lg4[192 + lane];
    vint4   dv1 = dp4[64 + lane];

    // masked pivot from already-loaded data (no extra serial loads)
    const int   d0 = __builtin_amdgcn_readfirstlane(dv0.x);
    const float l0 = __uint_as_float(
        __builtin_amdgcn_readfirstlane(__float_as_uint(aL0.y)));
    const float x0 = d0 ? -FLT_MAX : l0;   // jnp.finfo(float32).min

    const bool hi = (lane & 32) != 0;
    const int  i  = (2 * lane) & 63;
    int cnt = 0, dsum = 0;   // wave-uniform via ballot+popcount (SGPR math)

#define CONSUME(aL, aH, dv, VB, VD)                                           \
    {                                                                         \
        const unsigned long long beL = __ballot((aL).y > x0);                 \
        const unsigned long long boL = __ballot((aL).w > x0);                 \
        const unsigned long long beH = __ballot((VB) && ((aH).y > x0));       \
        const unsigned long long boH = __ballot((VB) && ((aH).w > x0));       \
        const unsigned long long we = hi ? beH : beL;                         \
        const unsigned long long wo = hi ? boH : boL;                         \
        const unsigned re = (unsigned)(we >> i);                              \
        const unsigned ro = (unsigned)(wo >> i);                              \
        cnt  += __popcll(__ballot((VD) && ((dv).x == 0) && (re & 1)));        \
        cnt  += __popcll(__ballot((VD) && ((dv).y == 0) && (ro & 1)));        \
        cnt  += __popcll(__ballot((VD) && ((dv).z == 0) && ((re >> 1) & 1))); \
        cnt  += __popcll(__ballot((VD) && ((dv).w == 0) && ((ro >> 1) & 1))); \
        dsum += __popcll(__ballot((VD) && ((dv).x != 0)));                    \
        dsum += __popcll(__ballot((VD) && ((dv).y != 0)));                    \
        dsum += __popcll(__ballot((VD) && ((dv).z != 0)));                    \
        dsum += __popcll(__ballot((VD) && ((dv).w != 0)));                    \
    }

    // ---- steady state: consume m, then issue m+2 (1 group in flight) ----
    CONSUME(aL0, aH0, dv0, true, true);
    vfloat4 aL2 = lg4[256 + lane];
    vfloat4 aH2 = lg4[320 + lane];
    vint4   dv2 = dp4[128 + lane];

    CONSUME(aL1, aH1, dv1, true, true);
    // group 3 tails: aH3 chunk 448+lane valid iff lane<52; dv3 192+lane iff lane<58.
    // Invalid lanes clamp to last in-bounds chunk and are predicated out below.
    const int cH3 = (lane < 52) ? (448 + lane) : (CHUNKS_L - 1);
    const int g3  = (lane < 58) ? (192 + lane) : (CHUNKS_D - 1);
    vfloat4 aL3 = lg4[384 + lane];   // 384+63 = 447 < 500: all lanes valid
    vfloat4 aH3 = lg4[cH3];
    vint4   dv3 = dp4[g3];

    CONSUME(aL2, aH2, dv2, true, true);
    CONSUME(aL3, aH3, dv3, (lane < 52), (lane < 58));
#undef CONSUME

    if (lane == 0) {
        const float pos  = (float)cnt;
        const float itk  = (pos < (float)TOP_K) ? 1.0f : 0.0f;
        const float ndcg = (itk != 0.0f)
            ? (0.69314718055994530942f / logf(pos + 2.0f)) : 0.0f;
        const float w    = (dsum != NUM_EVAL_NEG) ? 1.0f : 0.0f;
        out[user]                 = itk;
        out[num_users + user]     = ndcg;
        out[2 * num_users + user] = w;
    }
}

extern "C" void kernel_launch(void* const* d_in, const int* in_sizes, int n_in,
                              void* d_out, int out_size, void* d_ws, size_t ws_size,
                              hipStream_t stream) {
    const float* logits = (const float*)d_in[0];  // (N*ROW, 1, 2) fp32
    const int*   dup    = (const int*)d_in[1];    // (N*ROW, 1, 1) int32
    float* out = (float*)d_out;                   // 3*N floats

    const int num_users = in_sizes[0] / (2 * ROW);
    const int grid = (num_users + USERS_PER_BLOCK - 1) / USERS_PER_BLOCK;

    metric_kernel<<<grid, 256, 0, stream>>>(logits, dup, out, num_users);
}